// Round 6
// baseline (306.736 us; speedup 1.0000x reference)
//
#include <hip/hip_runtime.h>
#include <hip/hip_bf16.h>
#include <math.h>

#define BB 2
#define LL 2048
#define DM 1024
#define DS 16
#define DI 2048
#define KX 33          // 1 + 2*D_STATE
#define D2 (2*DI)      // 4096
#define NC 32          // scan chunks
#define LC 64          // chunk length (NC*LC == LL)
#define SEGS 32        // xproj d-segments
#define SEGW 64        // d per segment

typedef __attribute__((ext_vector_type(8))) short short8v;   // 8 bf16 (4 VGPRs)
typedef __attribute__((ext_vector_type(4))) float f32x4;

__device__ __forceinline__ void gload16(const void* g, void* l) {
    __builtin_amdgcn_global_load_lds((const __attribute__((address_space(1))) void*)g,
                                     (__attribute__((address_space(3))) void*)l,
                                     16, 0, 0);
}

__device__ __forceinline__ ushort tobf(float v) {
    __hip_bfloat16 h = __float2bfloat16(v);
    return *(ushort*)&h;
}

// ---------------------------------------------------------------------------
// fp32 -> bf16 (RNE) conversion, 8 elems/thread
// ---------------------------------------------------------------------------
__global__ __launch_bounds__(256) void cvt_bf16_k(const float* __restrict__ in,
                                                  ushort* __restrict__ o, int n8) {
    int i = blockIdx.x * 256 + threadIdx.x;
    if (i >= n8) return;
    float4 a = *(const float4*)&in[(size_t)i * 8];
    float4 b = *(const float4*)&in[(size_t)i * 8 + 4];
    float v[8] = {a.x, a.y, a.z, a.w, b.x, b.y, b.z, b.w};
    ushort u[8];
    #pragma unroll
    for (int j = 0; j < 8; j++) u[j] = tobf(v[j]);
    *(ushort4*)&o[(size_t)i * 8]     = make_ushort4(u[0], u[1], u[2], u[3]);
    *(ushort4*)&o[(size_t)i * 8 + 4] = make_ushort4(u[4], u[5], u[6], u[7]);
}

// ---------------------------------------------------------------------------
// NT bf16 MFMA GEMM (m97 structure), 128x128 tile, 4 waves, 4x4 fragments.
// MODE 0: C row=d, col=bl -> xz[((col>>11)*D2 + row)*LL + (col&2047)]
// MODE 1: C row=bl, col=m -> out[row*DM + col]
// ---------------------------------------------------------------------------
template<int K, int MODE>
__global__ __launch_bounds__(256) void mfma_nt_k(const ushort* __restrict__ A,
                                                 const ushort* __restrict__ Bm,
                                                 float* __restrict__ C) {
    __shared__ ushort Als[128][32];
    __shared__ ushort Bls[128][32];
    const int n0 = blockIdx.x * 128;
    const int m0 = blockIdx.y * 128;
    const int tid = threadIdx.x;
    const int w = tid >> 6, lane = tid & 63;
    const int wr = (w >> 1) * 64, wc = (w & 1) * 64;
    const int lrow = lane & 15;
    const int kq = lane >> 4;

    const int srow = (lane >> 2);
    const int skof = (lane & 3) * 8;

    f32x4 acc[4][4] = {};
    for (int k0 = 0; k0 < K; k0 += 32) {
        #pragma unroll
        for (int j = 0; j < 2; j++) {
            const int rbase = w * 32 + j * 16;
            gload16(&A [(size_t)(m0 + rbase + srow) * K + k0 + skof], &Als[rbase][0]);
            gload16(&Bm[(size_t)(n0 + rbase + srow) * K + k0 + skof], &Bls[rbase][0]);
        }
        __syncthreads();
        short8v af[4], bf[4];
        #pragma unroll
        for (int i = 0; i < 4; i++) {
            af[i] = *(const short8v*)&Als[wr + i * 16 + lrow][kq * 8];
            bf[i] = *(const short8v*)&Bls[wc + i * 16 + lrow][kq * 8];
        }
        #pragma unroll
        for (int i = 0; i < 4; i++)
            #pragma unroll
            for (int jn = 0; jn < 4; jn++)
                acc[i][jn] = __builtin_amdgcn_mfma_f32_16x16x32_bf16(af[i], bf[jn], acc[i][jn], 0, 0, 0);
        __syncthreads();
    }
    #pragma unroll
    for (int i = 0; i < 4; i++) {
        #pragma unroll
        for (int jn = 0; jn < 4; jn++) {
            #pragma unroll
            for (int r = 0; r < 4; r++) {
                int row = m0 + wr + i * 16 + (lane >> 4) * 4 + r;
                int col = n0 + wc + jn * 16 + (lane & 15);
                size_t off;
                if constexpr (MODE == 0)
                    off = ((size_t)(col >> 11) * D2 + row) * LL + (col & (LL - 1));
                else
                    off = (size_t)row * DM + col;
                C[off] = acc[i][jn][r];
            }
        }
    }
}

// ---------------------------------------------------------------------------
// Depthwise causal conv(4) + bias + SiLU on x-half of xz -> xc (vectorized)
// ---------------------------------------------------------------------------
__global__ __launch_bounds__(256) void conv_silu_k(const float* __restrict__ xz,
                                                   const float* __restrict__ cw,
                                                   const float* __restrict__ cb,
                                                   float* __restrict__ xc) {
    const int row = blockIdx.x;             // 0..B*DI-1
    const int b = row >> 11, d = row & (DI - 1);
    const float* xr = xz + ((size_t)b * D2 + d) * LL;
    float4 wv = *(const float4*)&cw[d * 4];
    const float w0 = wv.x, w1 = wv.y, w2 = wv.z, w3 = wv.w;
    const float bias = cb[d];
    const int l0 = threadIdx.x * 8;
    float4 pm = (l0 >= 4) ? *(const float4*)&xr[l0 - 4] : make_float4(0.f, 0.f, 0.f, 0.f);
    float4 c0 = *(const float4*)&xr[l0];
    float4 c1 = *(const float4*)&xr[l0 + 4];
    float buf[11] = {pm.y, pm.z, pm.w, c0.x, c0.y, c0.z, c0.w, c1.x, c1.y, c1.z, c1.w};
    float o[8];
    #pragma unroll
    for (int j = 0; j < 8; j++) {
        float s = fmaf(buf[j], w0, fmaf(buf[j + 1], w1,
                  fmaf(buf[j + 2], w2, fmaf(buf[j + 3], w3, bias))));
        o[j] = s / (1.f + expf(-s));
    }
    float* out = xc + ((size_t)b * DI + d) * LL + l0;
    *(float4*)&out[0] = make_float4(o[0], o[1], o[2], o[3]);
    *(float4*)&out[4] = make_float4(o[4], o[5], o[6], o[7]);
}

// ---------------------------------------------------------------------------
// x_dbl partials: part[seg][b][k][l] = sum_{d in seg(64)} xc[b][d][l]*Wx[k][d]
// ---------------------------------------------------------------------------
__global__ __launch_bounds__(256) void xproj_partial_k(const float* __restrict__ xc,
                                                       const float* __restrict__ Wx,
                                                       float* __restrict__ part) {
    const int lt = blockIdx.x;             // 0..7  (512 l each)
    const int seg = blockIdx.y;            // 0..31 (64 d each)
    const int tid = threadIdx.x;
    const int bl0 = lt * 512;
    const int b = bl0 >> 11;
    const int l = (bl0 & (LL - 1)) + tid * 2;
    const int dbase = seg * SEGW;

    __shared__ float w[SEGW][36];          // [dd][kk], row padded to 36
    for (int kk = tid >> 6; kk < KX; kk += 4)
        w[tid & 63][kk] = Wx[(size_t)kk * DI + dbase + (tid & 63)];
    __syncthreads();

    float2 acc[KX];
    #pragma unroll
    for (int kk = 0; kk < KX; kk++) acc[kk] = make_float2(0.f, 0.f);

    const float* xb = xc + ((size_t)b * DI + dbase) * LL + l;
    #pragma unroll 4
    for (int dd = 0; dd < SEGW; dd++) {
        float2 xv = *(const float2*)&xb[(size_t)dd * LL];
        #pragma unroll
        for (int q = 0; q < 8; q++) {
            float4 wv = *(const float4*)&w[dd][q * 4];
            float wa[4] = {wv.x, wv.y, wv.z, wv.w};
            #pragma unroll
            for (int t = 0; t < 4; t++) {
                acc[q * 4 + t].x = fmaf(xv.x, wa[t], acc[q * 4 + t].x);
                acc[q * 4 + t].y = fmaf(xv.y, wa[t], acc[q * 4 + t].y);
            }
        }
        float wl = w[dd][32];
        acc[32].x = fmaf(xv.x, wl, acc[32].x);
        acc[32].y = fmaf(xv.y, wl, acc[32].y);
    }
    #pragma unroll
    for (int kk = 0; kk < KX; kk++)
        *(float2*)&part[(((size_t)seg * BB + b) * KX + kk) * LL + l] = acc[kk];
}

__global__ __launch_bounds__(256) void xproj_reduce_k(const float* __restrict__ part,
                                                      float* __restrict__ xdbl) {
    const int i = blockIdx.x * 256 + threadIdx.x;    // float4 index
    if (i >= (BB * KX * LL) / 4) return;
    float4 s = make_float4(0.f, 0.f, 0.f, 0.f);
    #pragma unroll
    for (int seg = 0; seg < SEGS; seg++) {
        float4 v = *(const float4*)&part[(size_t)seg * BB * KX * LL + (size_t)i * 4];
        s.x += v.x; s.y += v.y; s.z += v.z; s.w += v.w;
    }
    *(float4*)&xdbl[(size_t)i * 4] = s;
}

// ---------------------------------------------------------------------------
// Local scan v2: thread = (d, n-half). 8 states/thread, one shfl per step.
// dt computed inline (softplus); cum -> xz x-half (dead after conv);
// y0 (+x*Dskip) in-place over xc; terminal h -> hloc; chunk dt-sum -> sumc.
// Single barrier per chunk (B/C/dtraw staged whole-chunk).
// ---------------------------------------------------------------------------
__global__ __launch_bounds__(256) void scan_local_k(float* xz,     // x-half: cum out; z-half untouched
                                                    float* xc,     // x in / y0 out
                                                    const float* __restrict__ xdbl,
                                                    const float* __restrict__ Alog,
                                                    const float* __restrict__ Wdt,
                                                    const float* __restrict__ bdt,
                                                    const float* __restrict__ Dskip,
                                                    float* __restrict__ hloc,
                                                    float* __restrict__ sumc) {
    const int blk = blockIdx.x;            // c*32 + b*16 + dblk
    const int dblk = blk & 15;
    const int b = (blk >> 4) & 1;
    const int c = blk >> 5;
    const int tid = threadIdx.x;
    const int dl = tid >> 1, nh = tid & 1, n0 = nh * 8;
    const int d = dblk * 128 + dl;

    __shared__ float Bt[LC][16], Ct[LC][16], sdtr[LC];   // 8.5 KB

    float a2[8], h[8];
    #pragma unroll
    for (int n = 0; n < 8; n++) {
        a2[n] = -expf(Alog[(size_t)d * DS + n0 + n]) * 1.44269504f;
        h[n] = 0.f;
    }
    const float wdt = Wdt[d], bdtv = bdt[d], dsk = Dskip[d];

    for (int i = tid; i < LC * 16; i += 256) {
        int n = i & 15, l = i >> 4;
        Bt[l][n] = xdbl[((size_t)b * KX + 1 + n) * LL + c * LC + l];
        Ct[l][n] = xdbl[((size_t)b * KX + 17 + n) * LL + c * LC + l];
    }
    if (tid < LC) sdtr[tid] = xdbl[(size_t)b * KX * LL + c * LC + tid];
    __syncthreads();

    float cum = 0.f;
    float* cumrow = xz + ((size_t)b * D2 + d) * LL + c * LC;   // x-half
    float* xrow   = xc + ((size_t)b * DI + d) * LL + c * LC;

    for (int g = 0; g < LC; g += 16) {
        float4 x0 = *(const float4*)&xrow[g];
        float4 x1 = *(const float4*)&xrow[g + 4];
        float4 x2 = *(const float4*)&xrow[g + 8];
        float4 x3 = *(const float4*)&xrow[g + 12];
        float xr[16] = {x0.x,x0.y,x0.z,x0.w, x1.x,x1.y,x1.z,x1.w,
                        x2.x,x2.y,x2.z,x2.w, x3.x,x3.y,x3.z,x3.w};
        float cwv[16];
        #pragma unroll
        for (int j = 0; j < 16; j++) {
            const int l = g + j;
            float v = fmaf(wdt, sdtr[l], bdtv);
            float dt = fmaxf(v, 0.f) + log1pf(expf(-fabsf(v)));   // softplus
            cum += dt; cwv[j] = cum;
            float u = dt * xr[j];
            float4 b0 = *(const float4*)&Bt[l][n0];
            float4 b1 = *(const float4*)&Bt[l][n0 + 4];
            float4 q0 = *(const float4*)&Ct[l][n0];
            float4 q1 = *(const float4*)&Ct[l][n0 + 4];
            float bv[8] = {b0.x,b0.y,b0.z,b0.w, b1.x,b1.y,b1.z,b1.w};
            float cv[8] = {q0.x,q0.y,q0.z,q0.w, q1.x,q1.y,q1.z,q1.w};
            float y = 0.f;
            #pragma unroll
            for (int n = 0; n < 8; n++) {
                h[n] = fmaf(exp2f(a2[n] * dt), h[n], u * bv[n]);
                y = fmaf(h[n], cv[n], y);
            }
            y += __shfl_xor(y, 1);          // combine the two n-halves
            xr[j] = fmaf(xr[j], dsk, y);
        }
        if (nh == 0) {
            *(float4*)&xrow[g]      = make_float4(xr[0],  xr[1],  xr[2],  xr[3]);
            *(float4*)&xrow[g + 4]  = make_float4(xr[4],  xr[5],  xr[6],  xr[7]);
            *(float4*)&xrow[g + 8]  = make_float4(xr[8],  xr[9],  xr[10], xr[11]);
            *(float4*)&xrow[g + 12] = make_float4(xr[12], xr[13], xr[14], xr[15]);
        } else {
            *(float4*)&cumrow[g]      = make_float4(cwv[0],  cwv[1],  cwv[2],  cwv[3]);
            *(float4*)&cumrow[g + 4]  = make_float4(cwv[4],  cwv[5],  cwv[6],  cwv[7]);
            *(float4*)&cumrow[g + 8]  = make_float4(cwv[8],  cwv[9],  cwv[10], cwv[11]);
            *(float4*)&cumrow[g + 12] = make_float4(cwv[12], cwv[13], cwv[14], cwv[15]);
        }
    }
    float* hp = &hloc[(((size_t)c * BB + b) * DI + d) * DS + n0];
    *(float4*)&hp[0] = make_float4(h[0], h[1], h[2], h[3]);
    *(float4*)&hp[4] = make_float4(h[4], h[5], h[6], h[7]);
    if (nh) sumc[((size_t)c * BB + b) * DI + d] = cum;
}

// ---------------------------------------------------------------------------
// Combine: serial over 32 chunk boundaries; compact chunk dt-sums.
// ---------------------------------------------------------------------------
__global__ __launch_bounds__(256) void combine2_k(const float* __restrict__ hloc,
                                                  const float* __restrict__ sumc,
                                                  const float* __restrict__ Alog,
                                                  float* __restrict__ hin) {
    const int i = blockIdx.x * 256 + threadIdx.x;   // (b*DI+d)*16+n
    const int n = i & 15;
    const int bd = i >> 4;
    const int d = bd & (DI - 1);
    const float a2 = -expf(Alog[(size_t)d * DS + n]) * 1.44269504f;
    float h = 0.f;
    for (int c = 0; c < NC; c++) {
        size_t idx = ((size_t)c * BB * DI + bd) * DS + n;
        float t = hloc[idx];
        hin[idx] = h;
        float P = exp2f(a2 * sumc[(size_t)c * BB * DI + bd]);
        h = fmaf(P, h, t);
    }
}

// ---------------------------------------------------------------------------
// y fixup: y = (y0 + sum_n C[n,l]*exp2(a2*cum[l])*hin[n]) * silu(z),
// silu computed inline from raw z; emitted transposed bf16 ybf[(b*L+l)][d].
// ---------------------------------------------------------------------------
__global__ __launch_bounds__(256) void yfix_k(const float* __restrict__ xz,   // cum x-half, z z-half
                                              const float* __restrict__ xc,   // y0
                                              const float* __restrict__ xdbl,
                                              const float* __restrict__ Alog,
                                              const float* __restrict__ hin,
                                              ushort* __restrict__ ybf) {
    const int bl0 = blockIdx.x * 64;
    const int b = bl0 >> 11, l0 = bl0 & (LL - 1);
    const int d0 = blockIdx.y * 64;
    const int c = l0 / LC;                    // LC==64: one chunk per l-tile
    const int tid = threadIdx.x;
    const int dl = tid & 63;
    const int lq = tid >> 6;                  // 0..3 -> 16 l's each
    const int d = d0 + dl;

    __shared__ float Ctile[64][16];           // [l][n]
    __shared__ ushort sy[64][72];             // bf16 transpose tile (padded)

    {   // stage C
        int li = tid & 63, n4 = (tid >> 6) * 4;
        #pragma unroll
        for (int k = 0; k < 4; k++)
            Ctile[li][n4 + k] = xdbl[((size_t)b * KX + 17 + n4 + k) * LL + l0 + li];
    }
    float a2[16], hi[16];
    #pragma unroll
    for (int n = 0; n < 16; n++)
        a2[n] = -expf(Alog[(size_t)d * DS + n]) * 1.44269504f;
    {
        const float* hp = &hin[(((size_t)c * BB + b) * DI + d) * DS];
        float4 h0 = *(const float4*)&hp[0];
        float4 h1 = *(const float4*)&hp[4];
        float4 h2 = *(const float4*)&hp[8];
        float4 h3 = *(const float4*)&hp[12];
        float ht[16] = {h0.x,h0.y,h0.z,h0.w, h1.x,h1.y,h1.z,h1.w,
                        h2.x,h2.y,h2.z,h2.w, h3.x,h3.y,h3.z,h3.w};
        #pragma unroll
        for (int n = 0; n < 16; n++) hi[n] = ht[n];
    }
    const int lbase = l0 + lq * 16;
    const float* cumr = xz + ((size_t)b * D2 + d) * LL + lbase;        // x-half
    const float* y0r  = xc + ((size_t)b * DI + d) * LL + lbase;
    const float* zr   = xz + ((size_t)b * D2 + DI + d) * LL + lbase;   // raw z
    float4 c0v = *(const float4*)&cumr[0], c1v = *(const float4*)&cumr[4];
    float4 c2v = *(const float4*)&cumr[8], c3v = *(const float4*)&cumr[12];
    float4 y0v = *(const float4*)&y0r[0],  y1v = *(const float4*)&y0r[4];
    float4 y2v = *(const float4*)&y0r[8],  y3v = *(const float4*)&y0r[12];
    float4 z0v = *(const float4*)&zr[0],   z1v = *(const float4*)&zr[4];
    float4 z2v = *(const float4*)&zr[8],   z3v = *(const float4*)&zr[12];
    float cm[16] = {c0v.x,c0v.y,c0v.z,c0v.w, c1v.x,c1v.y,c1v.z,c1v.w,
                    c2v.x,c2v.y,c2v.z,c2v.w, c3v.x,c3v.y,c3v.z,c3v.w};
    float yv[16] = {y0v.x,y0v.y,y0v.z,y0v.w, y1v.x,y1v.y,y1v.z,y1v.w,
                    y2v.x,y2v.y,y2v.z,y2v.w, y3v.x,y3v.y,y3v.z,y3v.w};
    float zv[16] = {z0v.x,z0v.y,z0v.z,z0v.w, z1v.x,z1v.y,z1v.z,z1v.w,
                    z2v.x,z2v.y,z2v.z,z2v.w, z3v.x,z3v.y,z3v.z,z3v.w};
    __syncthreads();
    #pragma unroll
    for (int j = 0; j < 16; j++) {
        int lidx = lq * 16 + j;
        float4 a0 = *(const float4*)&Ctile[lidx][0];
        float4 a1 = *(const float4*)&Ctile[lidx][4];
        float4 a2v = *(const float4*)&Ctile[lidx][8];
        float4 a3 = *(const float4*)&Ctile[lidx][12];
        float cv[16] = {a0.x,a0.y,a0.z,a0.w, a1.x,a1.y,a1.z,a1.w,
                        a2v.x,a2v.y,a2v.z,a2v.w, a3.x,a3.y,a3.z,a3.w};
        float corr = 0.f;
        #pragma unroll
        for (int n = 0; n < 16; n++)
            corr = fmaf(cv[n] * hi[n], exp2f(a2[n] * cm[j]), corr);
        float z = zv[j];
        float zs = z / (1.f + expf(-z));
        float y = (yv[j] + corr) * zs;
        sy[lidx][dl] = tobf(y);
    }
    __syncthreads();
    {
        int lw = tid >> 2, p = tid & 3;
        uint4 v0 = *(const uint4*)&sy[lw][p * 16];
        uint4 v1 = *(const uint4*)&sy[lw][p * 16 + 8];
        ushort* orow = &ybf[((size_t)b * LL + l0 + lw) * DI + d0 + p * 16];
        *(uint4*)&orow[0] = v0;
        *(uint4*)&orow[8] = v1;
    }
}

// ---------------------------------------------------------------------------
extern "C" void kernel_launch(void* const* d_in, const int* in_sizes, int n_in,
                              void* d_out, int out_size, void* d_ws, size_t ws_size,
                              hipStream_t stream) {
    const float* hs   = (const float*)d_in[0];
    const float* Win  = (const float*)d_in[1];
    const float* cw   = (const float*)d_in[2];
    const float* cb   = (const float*)d_in[3];
    const float* Wx   = (const float*)d_in[4];
    const float* Wdt  = (const float*)d_in[5];
    const float* bdt  = (const float*)d_in[6];
    const float* Alog = (const float*)d_in[7];
    const float* Dsk  = (const float*)d_in[8];
    const float* Wout = (const float*)d_in[9];
    float* out = (float*)d_out;

    // layout (floats): total 31,592,448 = 126.4 MB (identical to known-good R5)
    float* xz    = (float*)d_ws;                           // 16,777,216
    float* xc    = xz    + (size_t)BB * D2 * LL;           //  8,388,608
    float* xdbl  = xc    + (size_t)BB * DI * LL;           //    135,168
    float* part  = xdbl  + (size_t)BB * KX * LL;           //  4,325,376 (lives gemm1..reduce only)
    float* hin   = part;                                   //  2,097,152 (combine -> yfix)
    float* convf = part  + (size_t)2097152;                //  4,194,304 f region

    ushort* Winb  = (ushort*)convf;                        // dead after gemm1
    ushort* hsb   = Winb + (size_t)D2 * DM;                // dead after gemm1
    float*  hloc  = (float*)hsb;                           // scan -> combine (2,097,152 f)
    float*  sumc  = (float*)convf;                         // scan -> combine (131,072 f, in dead Winb)
    ushort* ybf   = (ushort*)convf;                        // yfix -> gemm2 (all aliases dead)
    ushort* Woutb = (ushort*)hin;                          // written after yfix (hin dead)

    cvt_bf16_k<<<2048, 256, 0, stream>>>(Win, Winb, (D2 * DM) / 8);
    cvt_bf16_k<<<2048, 256, 0, stream>>>(hs, hsb, (BB * LL * DM) / 8);
    mfma_nt_k<DM, 0><<<dim3(32, 32), 256, 0, stream>>>(Winb, hsb, xz);
    conv_silu_k<<<BB * DI, 256, 0, stream>>>(xz, cw, cb, xc);
    xproj_partial_k<<<dim3(8, SEGS), 256, 0, stream>>>(xc, Wx, part);
    xproj_reduce_k<<<(BB * KX * LL / 4 + 255) / 256, 256, 0, stream>>>(part, xdbl);
    scan_local_k<<<NC * BB * 16, 256, 0, stream>>>(xz, xc, xdbl, Alog, Wdt, bdt, Dsk, hloc, sumc);
    combine2_k<<<(BB * DI * DS) / 256, 256, 0, stream>>>(hloc, sumc, Alog, hin);
    yfix_k<<<dim3((BB * LL) / 64, DI / 64), 256, 0, stream>>>(xz, xc, xdbl, Alog, hin, ybf);
    cvt_bf16_k<<<1024, 256, 0, stream>>>(Wout, Woutb, (DM * DI) / 8);
    mfma_nt_k<DI, 1><<<dim3(8, 32), 256, 0, stream>>>(ybf, Woutb, out);
}

// Round 7
// 265.542 us; speedup vs baseline: 1.1551x; 1.1551x over previous
//
#include <hip/hip_runtime.h>
#include <hip/hip_bf16.h>
#include <math.h>

#define BB 2
#define LL 2048
#define DM 1024
#define DS 16
#define DI 2048
#define KX 33          // 1 + 2*D_STATE
#define D2 (2*DI)      // 4096
#define NC 64          // scan chunks
#define LC 32          // chunk length (NC*LC == LL)
#define SEGS 32        // xproj d-segments
#define SEGW 64        // d per segment

typedef __attribute__((ext_vector_type(8))) short short8v;   // 8 bf16 (4 VGPRs)
typedef __attribute__((ext_vector_type(4))) float f32x4;

__device__ __forceinline__ void gload16(const void* g, void* l) {
    __builtin_amdgcn_global_load_lds((const __attribute__((address_space(1))) void*)g,
                                     (__attribute__((address_space(3))) void*)l,
                                     16, 0, 0);
}

__device__ __forceinline__ ushort tobf(float v) {
    __hip_bfloat16 h = __float2bfloat16(v);
    return *(ushort*)&h;
}

// ---------------------------------------------------------------------------
// fp32 -> bf16 (RNE) conversion, 8 elems/thread
// ---------------------------------------------------------------------------
__global__ __launch_bounds__(256) void cvt_bf16_k(const float* __restrict__ in,
                                                  ushort* __restrict__ o, int n8) {
    int i = blockIdx.x * 256 + threadIdx.x;
    if (i >= n8) return;
    float4 a = *(const float4*)&in[(size_t)i * 8];
    float4 b = *(const float4*)&in[(size_t)i * 8 + 4];
    float v[8] = {a.x, a.y, a.z, a.w, b.x, b.y, b.z, b.w};
    ushort u[8];
    #pragma unroll
    for (int j = 0; j < 8; j++) u[j] = tobf(v[j]);
    *(ushort4*)&o[(size_t)i * 8]     = make_ushort4(u[0], u[1], u[2], u[3]);
    *(ushort4*)&o[(size_t)i * 8 + 4] = make_ushort4(u[4], u[5], u[6], u[7]);
}

// ---------------------------------------------------------------------------
// NT bf16 MFMA GEMM (m97 structure), 128x128 tile, 4 waves, 4x4 fragments.
// MODE 0: C row=d, col=bl -> xz[((col>>11)*D2 + row)*LL + (col&2047)]
// MODE 1: C row=bl, col=m -> out[row*DM + col]
// ---------------------------------------------------------------------------
template<int K, int MODE>
__global__ __launch_bounds__(256) void mfma_nt_k(const ushort* __restrict__ A,
                                                 const ushort* __restrict__ Bm,
                                                 float* __restrict__ C) {
    __shared__ ushort Als[128][32];
    __shared__ ushort Bls[128][32];
    const int n0 = blockIdx.x * 128;
    const int m0 = blockIdx.y * 128;
    const int tid = threadIdx.x;
    const int w = tid >> 6, lane = tid & 63;
    const int wr = (w >> 1) * 64, wc = (w & 1) * 64;
    const int lrow = lane & 15;
    const int kq = lane >> 4;

    const int srow = (lane >> 2);
    const int skof = (lane & 3) * 8;

    f32x4 acc[4][4] = {};
    for (int k0 = 0; k0 < K; k0 += 32) {
        #pragma unroll
        for (int j = 0; j < 2; j++) {
            const int rbase = w * 32 + j * 16;
            gload16(&A [(size_t)(m0 + rbase + srow) * K + k0 + skof], &Als[rbase][0]);
            gload16(&Bm[(size_t)(n0 + rbase + srow) * K + k0 + skof], &Bls[rbase][0]);
        }
        __syncthreads();
        short8v af[4], bf[4];
        #pragma unroll
        for (int i = 0; i < 4; i++) {
            af[i] = *(const short8v*)&Als[wr + i * 16 + lrow][kq * 8];
            bf[i] = *(const short8v*)&Bls[wc + i * 16 + lrow][kq * 8];
        }
        #pragma unroll
        for (int i = 0; i < 4; i++)
            #pragma unroll
            for (int jn = 0; jn < 4; jn++)
                acc[i][jn] = __builtin_amdgcn_mfma_f32_16x16x32_bf16(af[i], bf[jn], acc[i][jn], 0, 0, 0);
        __syncthreads();
    }
    #pragma unroll
    for (int i = 0; i < 4; i++) {
        #pragma unroll
        for (int jn = 0; jn < 4; jn++) {
            #pragma unroll
            for (int r = 0; r < 4; r++) {
                int row = m0 + wr + i * 16 + (lane >> 4) * 4 + r;
                int col = n0 + wc + jn * 16 + (lane & 15);
                size_t off;
                if constexpr (MODE == 0)
                    off = ((size_t)(col >> 11) * D2 + row) * LL + (col & (LL - 1));
                else
                    off = (size_t)row * DM + col;
                C[off] = acc[i][jn][r];
            }
        }
    }
}

// ---------------------------------------------------------------------------
// Depthwise causal conv(4) + bias + SiLU on x-half of xz -> xc (vectorized)
// ---------------------------------------------------------------------------
__global__ __launch_bounds__(256) void conv_silu_k(const float* __restrict__ xz,
                                                   const float* __restrict__ cw,
                                                   const float* __restrict__ cb,
                                                   float* __restrict__ xc) {
    const int row = blockIdx.x;             // 0..B*DI-1
    const int b = row >> 11, d = row & (DI - 1);
    const float* xr = xz + ((size_t)b * D2 + d) * LL;
    float4 wv = *(const float4*)&cw[d * 4];
    const float w0 = wv.x, w1 = wv.y, w2 = wv.z, w3 = wv.w;
    const float bias = cb[d];
    const int l0 = threadIdx.x * 8;
    float4 pm = (l0 >= 4) ? *(const float4*)&xr[l0 - 4] : make_float4(0.f, 0.f, 0.f, 0.f);
    float4 c0 = *(const float4*)&xr[l0];
    float4 c1 = *(const float4*)&xr[l0 + 4];
    float buf[11] = {pm.y, pm.z, pm.w, c0.x, c0.y, c0.z, c0.w, c1.x, c1.y, c1.z, c1.w};
    float o[8];
    #pragma unroll
    for (int j = 0; j < 8; j++) {
        float s = fmaf(buf[j], w0, fmaf(buf[j + 1], w1,
                  fmaf(buf[j + 2], w2, fmaf(buf[j + 3], w3, bias))));
        o[j] = s / (1.f + __expf(-s));
    }
    float* out = xc + ((size_t)b * DI + d) * LL + l0;
    *(float4*)&out[0] = make_float4(o[0], o[1], o[2], o[3]);
    *(float4*)&out[4] = make_float4(o[4], o[5], o[6], o[7]);
}

// ---------------------------------------------------------------------------
// x_dbl partials: part[seg][b][k][l] = sum_{d in seg(64)} xc[b][d][l]*Wx[k][d]
// ---------------------------------------------------------------------------
__global__ __launch_bounds__(256) void xproj_partial_k(const float* __restrict__ xc,
                                                       const float* __restrict__ Wx,
                                                       float* __restrict__ part) {
    const int lt = blockIdx.x;             // 0..7  (512 l each)
    const int seg = blockIdx.y;            // 0..31 (64 d each)
    const int tid = threadIdx.x;
    const int bl0 = lt * 512;
    const int b = bl0 >> 11;
    const int l = (bl0 & (LL - 1)) + tid * 2;
    const int dbase = seg * SEGW;

    __shared__ float w[SEGW][36];          // [dd][kk], row padded to 36
    for (int kk = tid >> 6; kk < KX; kk += 4)
        w[tid & 63][kk] = Wx[(size_t)kk * DI + dbase + (tid & 63)];
    __syncthreads();

    float2 acc[KX];
    #pragma unroll
    for (int kk = 0; kk < KX; kk++) acc[kk] = make_float2(0.f, 0.f);

    const float* xb = xc + ((size_t)b * DI + dbase) * LL + l;
    #pragma unroll 4
    for (int dd = 0; dd < SEGW; dd++) {
        float2 xv = *(const float2*)&xb[(size_t)dd * LL];
        #pragma unroll
        for (int q = 0; q < 8; q++) {
            float4 wv = *(const float4*)&w[dd][q * 4];
            float wa[4] = {wv.x, wv.y, wv.z, wv.w};
            #pragma unroll
            for (int t = 0; t < 4; t++) {
                acc[q * 4 + t].x = fmaf(xv.x, wa[t], acc[q * 4 + t].x);
                acc[q * 4 + t].y = fmaf(xv.y, wa[t], acc[q * 4 + t].y);
            }
        }
        float wl = w[dd][32];
        acc[32].x = fmaf(xv.x, wl, acc[32].x);
        acc[32].y = fmaf(xv.y, wl, acc[32].y);
    }
    #pragma unroll
    for (int kk = 0; kk < KX; kk++)
        *(float2*)&part[(((size_t)seg * BB + b) * KX + kk) * LL + l] = acc[kk];
}

__global__ __launch_bounds__(256) void xproj_reduce_k(const float* __restrict__ part,
                                                      float* __restrict__ xdbl) {
    const int i = blockIdx.x * 256 + threadIdx.x;    // float4 index
    if (i >= (BB * KX * LL) / 4) return;
    float4 s = make_float4(0.f, 0.f, 0.f, 0.f);
    #pragma unroll
    for (int seg = 0; seg < SEGS; seg++) {
        float4 v = *(const float4*)&part[(size_t)seg * BB * KX * LL + (size_t)i * 4];
        s.x += v.x; s.y += v.y; s.z += v.z; s.w += v.w;
    }
    *(float4*)&xdbl[(size_t)i * 4] = s;
}

// ---------------------------------------------------------------------------
// Local scan v3: thread-per-d, 16 states in registers, no cross-lane ops.
// dt = softplus(wdt*dtraw+bdt) inline (fast intrinsics, once per (b,d,l)).
// cum -> xz x-half; y0 (+x*Dskip) in-place over xc; terminal h -> hloc;
// chunk dt-sum -> sumc. NC=64 chunks of LC=32 -> 4096 waves (4/SIMD).
// ---------------------------------------------------------------------------
__global__ __launch_bounds__(256) void scan_local_k(float* xz,     // x-half: cum out; z-half untouched
                                                    float* xc,     // x in / y0 out
                                                    const float* __restrict__ xdbl,
                                                    const float* __restrict__ Alog,
                                                    const float* __restrict__ Wdt,
                                                    const float* __restrict__ bdt,
                                                    const float* __restrict__ Dskip,
                                                    float* __restrict__ hloc,
                                                    float* __restrict__ sumc) {
    const int blk = blockIdx.x;            // c*16 + b*8 + dblk
    const int dblk = blk & 7;
    const int b = (blk >> 3) & 1;
    const int c = blk >> 4;
    const int tid = threadIdx.x;
    const int d = dblk * 256 + tid;

    __shared__ float Bt[LC][16], Ct[LC][16], sdtr[LC];   // 4.2 KB

    float a2[16], h[16];
    #pragma unroll
    for (int n = 0; n < 16; n++) {
        a2[n] = -expf(Alog[(size_t)d * DS + n]) * 1.44269504f;
        h[n] = 0.f;
    }
    const float wdt = Wdt[d], bdtv = bdt[d], dsk = Dskip[d];

    #pragma unroll
    for (int i = tid; i < LC * 16; i += 256) {           // 2 iters
        int n = i >> 5, l = i & 31;                      // coalesced 32-l runs
        Bt[l][n] = xdbl[((size_t)b * KX + 1 + n) * LL + c * LC + l];
        Ct[l][n] = xdbl[((size_t)b * KX + 17 + n) * LL + c * LC + l];
    }
    if (tid < LC) sdtr[tid] = xdbl[(size_t)b * KX * LL + c * LC + tid];
    __syncthreads();

    float cum = 0.f;
    float* cumrow = xz + ((size_t)b * D2 + d) * LL + c * LC;   // x-half
    float* xrow   = xc + ((size_t)b * DI + d) * LL + c * LC;

    for (int g = 0; g < LC; g += 16) {
        float4 x0 = *(const float4*)&xrow[g];
        float4 x1 = *(const float4*)&xrow[g + 4];
        float4 x2 = *(const float4*)&xrow[g + 8];
        float4 x3 = *(const float4*)&xrow[g + 12];
        float xr[16] = {x0.x,x0.y,x0.z,x0.w, x1.x,x1.y,x1.z,x1.w,
                        x2.x,x2.y,x2.z,x2.w, x3.x,x3.y,x3.z,x3.w};
        float cwv[16];
        #pragma unroll
        for (int j = 0; j < 16; j++) {
            const int l = g + j;
            float v = fmaf(wdt, sdtr[l], bdtv);
            float dt = fmaxf(v, 0.f) + __logf(1.f + __expf(-fabsf(v)));  // fast softplus
            cum += dt; cwv[j] = cum;
            float u = dt * xr[j];
            float4 b0 = *(const float4*)&Bt[l][0];
            float4 b1 = *(const float4*)&Bt[l][4];
            float4 b2 = *(const float4*)&Bt[l][8];
            float4 b3 = *(const float4*)&Bt[l][12];
            float4 q0 = *(const float4*)&Ct[l][0];
            float4 q1 = *(const float4*)&Ct[l][4];
            float4 q2 = *(const float4*)&Ct[l][8];
            float4 q3 = *(const float4*)&Ct[l][12];
            float bv[16] = {b0.x,b0.y,b0.z,b0.w, b1.x,b1.y,b1.z,b1.w,
                            b2.x,b2.y,b2.z,b2.w, b3.x,b3.y,b3.z,b3.w};
            float cv[16] = {q0.x,q0.y,q0.z,q0.w, q1.x,q1.y,q1.z,q1.w,
                            q2.x,q2.y,q2.z,q2.w, q3.x,q3.y,q3.z,q3.w};
            float ya = 0.f, yb = 0.f, yc = 0.f, yd = 0.f;
            #pragma unroll
            for (int n = 0; n < 4; n++) {
                h[n]      = fmaf(exp2f(a2[n]      * dt), h[n],      u * bv[n]);
                h[n + 4]  = fmaf(exp2f(a2[n + 4]  * dt), h[n + 4],  u * bv[n + 4]);
                h[n + 8]  = fmaf(exp2f(a2[n + 8]  * dt), h[n + 8],  u * bv[n + 8]);
                h[n + 12] = fmaf(exp2f(a2[n + 12] * dt), h[n + 12], u * bv[n + 12]);
                ya = fmaf(h[n],      cv[n],      ya);
                yb = fmaf(h[n + 4],  cv[n + 4],  yb);
                yc = fmaf(h[n + 8],  cv[n + 8],  yc);
                yd = fmaf(h[n + 12], cv[n + 12], yd);
            }
            xr[j] = fmaf(xr[j], dsk, (ya + yb) + (yc + yd));
        }
        *(float4*)&xrow[g]        = make_float4(xr[0],  xr[1],  xr[2],  xr[3]);
        *(float4*)&xrow[g + 4]    = make_float4(xr[4],  xr[5],  xr[6],  xr[7]);
        *(float4*)&xrow[g + 8]    = make_float4(xr[8],  xr[9],  xr[10], xr[11]);
        *(float4*)&xrow[g + 12]   = make_float4(xr[12], xr[13], xr[14], xr[15]);
        *(float4*)&cumrow[g]      = make_float4(cwv[0],  cwv[1],  cwv[2],  cwv[3]);
        *(float4*)&cumrow[g + 4]  = make_float4(cwv[4],  cwv[5],  cwv[6],  cwv[7]);
        *(float4*)&cumrow[g + 8]  = make_float4(cwv[8],  cwv[9],  cwv[10], cwv[11]);
        *(float4*)&cumrow[g + 12] = make_float4(cwv[12], cwv[13], cwv[14], cwv[15]);
    }
    float* hp = &hloc[(((size_t)c * BB + b) * DI + d) * DS];
    *(float4*)&hp[0]  = make_float4(h[0],  h[1],  h[2],  h[3]);
    *(float4*)&hp[4]  = make_float4(h[4],  h[5],  h[6],  h[7]);
    *(float4*)&hp[8]  = make_float4(h[8],  h[9],  h[10], h[11]);
    *(float4*)&hp[12] = make_float4(h[12], h[13], h[14], h[15]);
    sumc[((size_t)c * BB + b) * DI + d] = cum;
}

// ---------------------------------------------------------------------------
// Combine: serial over 64 chunk boundaries, IN-PLACE (hloc becomes hin).
// ---------------------------------------------------------------------------
__global__ __launch_bounds__(256) void combine2_k(float* __restrict__ hloc,
                                                  const float* __restrict__ sumc,
                                                  const float* __restrict__ Alog) {
    const int i = blockIdx.x * 256 + threadIdx.x;   // (b*DI+d)*16+n
    const int n = i & 15;
    const int bd = i >> 4;
    const int d = bd & (DI - 1);
    const float a2 = -expf(Alog[(size_t)d * DS + n]) * 1.44269504f;
    float h = 0.f;
    for (int c = 0; c < NC; c++) {
        size_t idx = ((size_t)c * BB * DI + bd) * DS + n;
        float t = hloc[idx];
        hloc[idx] = h;                              // h entering chunk c
        float P = exp2f(a2 * sumc[(size_t)c * BB * DI + bd]);
        h = fmaf(P, h, t);
    }
}

// ---------------------------------------------------------------------------
// y fixup: y = (y0 + sum_n C[n,l]*exp2(a2*cum[l])*hin[n]) * silu(z),
// silu inline from raw z; emitted transposed bf16 ybf[(b*L+l)][d].
// ---------------------------------------------------------------------------
__global__ __launch_bounds__(256) void yfix_k(const float* __restrict__ xz,   // cum x-half, z z-half
                                              const float* __restrict__ xc,   // y0
                                              const float* __restrict__ xdbl,
                                              const float* __restrict__ Alog,
                                              const float* __restrict__ hin,
                                              ushort* __restrict__ ybf) {
    const int bl0 = blockIdx.x * 64;
    const int b = bl0 >> 11, l0 = bl0 & (LL - 1);
    const int d0 = blockIdx.y * 64;
    const int tid = threadIdx.x;
    const int dl = tid & 63;
    const int lq = tid >> 6;                  // 0..3 -> 16 l's each
    const int d = d0 + dl;
    const int lbase = l0 + lq * 16;
    const int c = lbase / LC;                 // chunk of this 16-l subgroup

    __shared__ float Ctile[64][16];           // [l][n]
    __shared__ ushort sy[64][72];             // bf16 transpose tile (padded)

    {   // stage C
        int li = tid & 63, n4 = (tid >> 6) * 4;
        #pragma unroll
        for (int k = 0; k < 4; k++)
            Ctile[li][n4 + k] = xdbl[((size_t)b * KX + 17 + n4 + k) * LL + l0 + li];
    }
    float a2[16], hi[16];
    #pragma unroll
    for (int n = 0; n < 16; n++)
        a2[n] = -expf(Alog[(size_t)d * DS + n]) * 1.44269504f;
    {
        const float* hp = &hin[(((size_t)c * BB + b) * DI + d) * DS];
        float4 h0 = *(const float4*)&hp[0];
        float4 h1 = *(const float4*)&hp[4];
        float4 h2 = *(const float4*)&hp[8];
        float4 h3 = *(const float4*)&hp[12];
        float ht[16] = {h0.x,h0.y,h0.z,h0.w, h1.x,h1.y,h1.z,h1.w,
                        h2.x,h2.y,h2.z,h2.w, h3.x,h3.y,h3.z,h3.w};
        #pragma unroll
        for (int n = 0; n < 16; n++) hi[n] = ht[n];
    }
    const float* cumr = xz + ((size_t)b * D2 + d) * LL + lbase;        // x-half
    const float* y0r  = xc + ((size_t)b * DI + d) * LL + lbase;
    const float* zr   = xz + ((size_t)b * D2 + DI + d) * LL + lbase;   // raw z
    float4 c0v = *(const float4*)&cumr[0], c1v = *(const float4*)&cumr[4];
    float4 c2v = *(const float4*)&cumr[8], c3v = *(const float4*)&cumr[12];
    float4 y0v = *(const float4*)&y0r[0],  y1v = *(const float4*)&y0r[4];
    float4 y2v = *(const float4*)&y0r[8],  y3v = *(const float4*)&y0r[12];
    float4 z0v = *(const float4*)&zr[0],   z1v = *(const float4*)&zr[4];
    float4 z2v = *(const float4*)&zr[8],   z3v = *(const float4*)&zr[12];
    float cm[16] = {c0v.x,c0v.y,c0v.z,c0v.w, c1v.x,c1v.y,c1v.z,c1v.w,
                    c2v.x,c2v.y,c2v.z,c2v.w, c3v.x,c3v.y,c3v.z,c3v.w};
    float yv[16] = {y0v.x,y0v.y,y0v.z,y0v.w, y1v.x,y1v.y,y1v.z,y1v.w,
                    y2v.x,y2v.y,y2v.z,y2v.w, y3v.x,y3v.y,y3v.z,y3v.w};
    float zv[16] = {z0v.x,z0v.y,z0v.z,z0v.w, z1v.x,z1v.y,z1v.z,z1v.w,
                    z2v.x,z2v.y,z2v.z,z2v.w, z3v.x,z3v.y,z3v.z,z3v.w};
    __syncthreads();
    #pragma unroll
    for (int j = 0; j < 16; j++) {
        int lidx = lq * 16 + j;
        float4 a0 = *(const float4*)&Ctile[lidx][0];
        float4 a1 = *(const float4*)&Ctile[lidx][4];
        float4 a2v = *(const float4*)&Ctile[lidx][8];
        float4 a3 = *(const float4*)&Ctile[lidx][12];
        float cv[16] = {a0.x,a0.y,a0.z,a0.w, a1.x,a1.y,a1.z,a1.w,
                        a2v.x,a2v.y,a2v.z,a2v.w, a3.x,a3.y,a3.z,a3.w};
        float corr = 0.f;
        #pragma unroll
        for (int n = 0; n < 16; n++)
            corr = fmaf(cv[n] * hi[n], exp2f(a2[n] * cm[j]), corr);
        float z = zv[j];
        float zs = z / (1.f + __expf(-z));
        float y = (yv[j] + corr) * zs;
        sy[lidx][dl] = tobf(y);
    }
    __syncthreads();
    {
        int lw = tid >> 2, p = tid & 3;
        uint4 v0 = *(const uint4*)&sy[lw][p * 16];
        uint4 v1 = *(const uint4*)&sy[lw][p * 16 + 8];
        ushort* orow = &ybf[((size_t)b * LL + l0 + lw) * DI + d0 + p * 16];
        *(uint4*)&orow[0] = v0;
        *(uint4*)&orow[8] = v1;
    }
}

// ---------------------------------------------------------------------------
extern "C" void kernel_launch(void* const* d_in, const int* in_sizes, int n_in,
                              void* d_out, int out_size, void* d_ws, size_t ws_size,
                              hipStream_t stream) {
    const float* hs   = (const float*)d_in[0];
    const float* Win  = (const float*)d_in[1];
    const float* cw   = (const float*)d_in[2];
    const float* cb   = (const float*)d_in[3];
    const float* Wx   = (const float*)d_in[4];
    const float* Wdt  = (const float*)d_in[5];
    const float* bdt  = (const float*)d_in[6];
    const float* Alog = (const float*)d_in[7];
    const float* Dsk  = (const float*)d_in[8];
    const float* Wout = (const float*)d_in[9];
    float* out = (float*)d_out;

    // layout (floats): total 31,592,448 = 126.4 MB (identical to known-good R5/R6)
    float* xz    = (float*)d_ws;                           // 16,777,216
    float* xc    = xz    + (size_t)BB * D2 * LL;           //  8,388,608
    float* xdbl  = xc    + (size_t)BB * DI * LL;           //    135,168
    float* part  = xdbl  + (size_t)BB * KX * LL;           //  4,325,376 slot (gemm1..reduce)
    float* hloc  = part;                                   //  4,194,304 (scan -> combine(in-place) -> yfix)
    float* convf = part  + (size_t)2097152 * 2 + 131072;   //  region = part + 4,325,376

    // NOTE: convf must start right after the part slot:
    convf = part + (size_t)4325376;                        //  4,194,304 f region (Winb|hsb / ybf)

    ushort* Winb  = (ushort*)convf;                        // dead after gemm1
    ushort* hsb   = Winb + (size_t)D2 * DM;                // dead after gemm1
    float*  sumc  = (float*)convf;                         // scan -> combine (262,144 f, in dead Winb)
    ushort* ybf   = (ushort*)convf;                        // yfix -> gemm2 (sumc dead by yfix)
    ushort* Woutb = (ushort*)part;                         // written after yfix (hloc dead)

    cvt_bf16_k<<<2048, 256, 0, stream>>>(Win, Winb, (D2 * DM) / 8);
    cvt_bf16_k<<<2048, 256, 0, stream>>>(hs, hsb, (BB * LL * DM) / 8);
    mfma_nt_k<DM, 0><<<dim3(32, 32), 256, 0, stream>>>(Winb, hsb, xz);
    conv_silu_k<<<BB * DI, 256, 0, stream>>>(xz, cw, cb, xc);
    xproj_partial_k<<<dim3(8, SEGS), 256, 0, stream>>>(xc, Wx, part);
    xproj_reduce_k<<<(BB * KX * LL / 4 + 255) / 256, 256, 0, stream>>>(part, xdbl);
    scan_local_k<<<NC * BB * 8, 256, 0, stream>>>(xz, xc, xdbl, Alog, Wdt, bdt, Dsk, hloc, sumc);
    combine2_k<<<(BB * DI * DS) / 256, 256, 0, stream>>>(hloc, sumc, Alog);
    yfix_k<<<dim3((BB * LL) / 64, DI / 64), 256, 0, stream>>>(xz, xc, xdbl, Alog, hloc, ybf);
    cvt_bf16_k<<<1024, 256, 0, stream>>>(Wout, Woutb, (DM * DI) / 8);
    mfma_nt_k<DI, 1><<<dim3(8, 32), 256, 0, stream>>>(ybf, Woutb, out);
}